// Round 5
// baseline (1688.698 us; speedup 1.0000x reference)
//
#include <hip/hip_runtime.h>
#include <hip/hip_bf16.h>
#include <stdint.h>

// ---------------------------------------------------------------------------
// BasisCustBiLSTM: per-sample basis-mixed BiLSTM.
//   k_meta / k_xbf / k_whhp / k_bias / k_mixwih / k_gemm : prep (unchanged)
//   k_recur R10 = R9 (dual-chain fused tagged records) + two serial-chain cuts:
//     (a) poll backoff: rounds>=2 insert s_sleep(8). R5..R9 all spin-read the
//         producer's destination line at max rate with vmcnt(0); the store
//         then queues behind a continuous reader convoy at the MALL. Backoff
//         thins the read queue exactly during the write window.
//     (b) publish-from-cell: wave 0 packs the record with two __shfl_xor and
//         fires the sc0sc1 store immediately after computing h -- no S3 wait,
//         no wave-3 wakeup, no hbst LDS round-trip.
//     Everything else (records {h01,h23,tag,0}, per-chain equality poll,
//     2-step periodic buffers, init, overwrite/launch safety) is R9 verbatim.
// ---------------------------------------------------------------------------

typedef __attribute__((ext_vector_type(8))) __bf16 bf16x8;
typedef __attribute__((ext_vector_type(4))) __bf16 bf16x4;
typedef __attribute__((ext_vector_type(4))) float  f32x4;
typedef __attribute__((ext_vector_type(4))) unsigned u32x4;
typedef __attribute__((ext_vector_type(2))) unsigned u32x2;

#define TT 256
#define BBATCH 32

__device__ __forceinline__ __bf16 f2bf(float f){
  unsigned u = __builtin_bit_cast(unsigned, f);
  unsigned short r = (unsigned short)((u + 0x7fffu + ((u >> 16) & 1u)) >> 16);
  return __builtin_bit_cast(__bf16, r);
}
__device__ __forceinline__ float sigm(float x){
  x = fminf(fmaxf(x, -30.f), 30.f);
  return 1.f / (1.f + __expf(-x));
}
__device__ __forceinline__ float tanh_(float x){
  x = fminf(fmaxf(x, -15.f), 15.f);
  float e = __expf(2.f * x);
  return (e - 1.f) / (e + 1.f);
}

// --- coherent (MALL-level) access helpers: sc0 sc1 = bypass L1+L2 ----------
__device__ __forceinline__ u32x4 ld_b128_coh(const void* p){
  u32x4 v;
  asm volatile("global_load_dwordx4 %0, %1, off sc0 sc1"
               : "=v"(v) : "v"(p) : "memory");
  return v;
}
__device__ __forceinline__ void st_b128_coh(void* p, u32x4 v){
  asm volatile("global_store_dwordx4 %0, %1, off sc0 sc1"
               :: "v"(p), "v"(v) : "memory");
}

// ---------------------------------------------------------------------------
__global__ void k_meta(const void* __restrict__ mask,
                       const int* __restrict__ meta_a, const int* __restrict__ meta_c,
                       const float* __restrict__ emb_a, const float* __restrict__ emb_c,
                       const float* __restrict__ W1, const float* __restrict__ b1,
                       const float* __restrict__ W2,
                       float* __restrict__ c_out, int* __restrict__ len_out)
{
  __shared__ int s_bad;
  __shared__ float q_sh[32][128];
  __shared__ float hid[32][64];
  const int tid = threadIdx.x;
  if (tid == 0) s_bad = 0;
  __syncthreads();

  if (tid < 32){
    const unsigned char* m8 = (const unsigned char*)mask;
    int cnt = 0, seen0 = 0, bad = 0;
    for (int t = 0; t < TT; ++t){
      unsigned char v = m8[tid * TT + t];
      if (v > 1) bad = 1;
      if (v){ if (seen0) bad = 1; cnt++; } else seen0 = 1;
    }
    if (tid == 0 && cnt != TT) bad = 1;
    if (bad) atomicAdd(&s_bad, 1);
    len_out[tid] = cnt;
  }
  {
    int b = tid >> 3, p = tid & 7;
    int a = meta_a[b], c = meta_c[b];
    for (int i = 0; i < 16; ++i){
      int qi = p * 16 + i;
      q_sh[b][qi] = (qi < 64) ? emb_a[a * 64 + qi] : emb_c[c * 64 + (qi - 64)];
    }
  }
  __syncthreads();
  if (s_bad){
    if (tid < 32){
      const int* m32 = (const int*)mask;
      int cnt = 0;
      for (int t = 0; t < TT; ++t) if (m32[tid * TT + t]) cnt++;
      len_out[tid] = cnt;
    }
  }
  {
    int b = tid >> 3, kg = tid & 7;
    for (int k8 = 0; k8 < 8; ++k8){
      int k = kg * 8 + k8;
      float s = b1[k];
      for (int i = 0; i < 128; ++i) s += q_sh[b][i] * W1[i * 64 + k];
      hid[b][k] = tanhf(s);
    }
  }
  __syncthreads();
  if (tid < 32){
    float lg[8]; float mx = -1e30f;
    for (int n = 0; n < 8; ++n){
      float s = 0.f;
      for (int k = 0; k < 64; ++k) s += hid[tid][k] * W2[k * 8 + n];
      lg[n] = s; mx = fmaxf(mx, s);
    }
    float den = 0.f;
    for (int n = 0; n < 8; ++n){ lg[n] = expf(lg[n] - mx); den += lg[n]; }
    for (int n = 0; n < 8; ++n) c_out[tid * 8 + n] = lg[n] / den;
  }
}

// ---------------------------------------------------------------------------
__global__ void k_xbf(const float* __restrict__ x, __bf16* __restrict__ xb)
{
  int i = blockIdx.x * 256 + threadIdx.x;
  if (i >= 524288) return;
  f32x4 a = *(const f32x4*)(x + (size_t)i * 8);
  f32x4 b = *(const f32x4*)(x + (size_t)i * 8 + 4);
  bf16x8 o;
  #pragma unroll
  for (int j = 0; j < 4; ++j){ o[j] = f2bf(a[j]); o[4 + j] = f2bf(b[j]); }
  *(bf16x8*)(xb + (size_t)i * 8) = o;
}

// ---------------------------------------------------------------------------
__global__ void k_whhp(const float* __restrict__ whh_f, const float* __restrict__ whh_r,
                       __bf16* __restrict__ outp)
{
  int idx = blockIdx.x * 256 + threadIdx.x;
  int lane = idx & 63; int grp = idx >> 6;
  int n  = grp & 7;  grp >>= 3;
  int kt = grp & 3;  grp >>= 2;
  int wv = grp & 3;  grp >>= 2;
  int wg = grp & 127; int dir = (grp >> 7) & 1;
  int col = lane & 15, quad = lane >> 4;
  int gate = col >> 2, jj = col & 3;
  int g = gate * 512 + wg * 4 + jj;
  int k = (wv * 4 + kt) * 32 + quad * 8;
  const float* Wb = dir ? whh_r : whh_f;
  const float* s = Wb + ((size_t)n * 2048 + g) * 512 + k;
  f32x4 a = *(const f32x4*)s, b = *(const f32x4*)(s + 4);
  bf16x8 o;
  #pragma unroll
  for (int j = 0; j < 4; ++j){ o[j] = f2bf(a[j]); o[4 + j] = f2bf(b[j]); }
  *(bf16x8*)(outp + (size_t)idx * 8) = o;
}

// ---------------------------------------------------------------------------
__global__ void k_bias(const float* __restrict__ b_f, const float* __restrict__ b_r,
                       const float* __restrict__ cb, float* __restrict__ bm)
{
  int idx = blockIdx.x * 256 + threadIdx.x;
  int dir = idx >> 16; int b = (idx >> 11) & 31; int g = idx & 2047;
  const float* bb = dir ? b_r : b_f;
  float s = 0.f;
  #pragma unroll
  for (int n = 0; n < 8; ++n) s += cb[b * 8 + n] * bb[n * 2048 + g];
  bm[idx] = s;
}

// ---------------------------------------------------------------------------
__global__ void k_mixwih(const float* __restrict__ Wb, const float* __restrict__ cb,
                         __bf16* __restrict__ wmix)
{
  __shared__ float cs[256];
  int tid = threadIdx.x;
  cs[tid] = cb[tid];
  __syncthreads();
  int idx = blockIdx.x * 256 + tid;
  int g = idx >> 6, k8 = idx & 63;
  float src[8][8];
  #pragma unroll
  for (int n = 0; n < 8; ++n){
    const float* p = Wb + ((size_t)n * 2048 + g) * 512 + k8 * 8;
    f32x4 lo = *(const f32x4*)p, hi = *(const f32x4*)(p + 4);
    #pragma unroll
    for (int j = 0; j < 4; ++j){ src[n][j] = lo[j]; src[n][4 + j] = hi[j]; }
  }
  for (int b = 0; b < 32; ++b){
    float acc[8] = {0,0,0,0,0,0,0,0};
    #pragma unroll
    for (int n = 0; n < 8; ++n){
      float cn = cs[b * 8 + n];
      #pragma unroll
      for (int j = 0; j < 8; ++j) acc[j] += cn * src[n][j];
    }
    bf16x8 o;
    #pragma unroll
    for (int j = 0; j < 8; ++j) o[j] = f2bf(acc[j]);
    *(bf16x8*)(wmix + ((size_t)b * 2048 + g) * 512 + k8 * 8) = o;
  }
}

// ---------------------------------------------------------------------------
__global__ __launch_bounds__(256) void k_gemm(const __bf16* __restrict__ xb,
                                              const __bf16* __restrict__ wmix,
                                              float* __restrict__ xp)
{
  __shared__ __bf16 As[128][72];
  __shared__ __bf16 Bs[128][72];
  const int tid = threadIdx.x, lane = tid & 63, wv = tid >> 6;
  const int quad = lane >> 4, c16 = lane & 15;
  const int wm_ = wv >> 1, wn_ = wv & 1;
  const int b = blockIdx.x >> 5, tile = blockIdx.x & 31;
  const int m0 = (tile >> 4) * 128, n0 = (tile & 15) * 128;
  const __bf16* Ap = xb + (size_t)b * TT * 512;
  const __bf16* Bp = wmix + (size_t)b * 2048 * 512;
  float* Cp = xp + (size_t)b * TT * 2048;

  f32x4 acc[4][4];
  #pragma unroll
  for (int i = 0; i < 4; ++i)
    #pragma unroll
    for (int j = 0; j < 4; ++j) acc[i][j] = (f32x4){0,0,0,0};

  for (int k0 = 0; k0 < 512; k0 += 64){
    __syncthreads();
    #pragma unroll
    for (int it = 0; it < 4; ++it){
      int r = it * 32 + (tid >> 3), c = (tid & 7) * 8;
      *(bf16x8*)&As[r][c] = *(const bf16x8*)(Ap + (size_t)(m0 + r) * 512 + k0 + c);
      *(bf16x8*)&Bs[r][c] = *(const bf16x8*)(Bp + (size_t)(n0 + r) * 512 + k0 + c);
    }
    __syncthreads();
    #pragma unroll
    for (int kt = 0; kt < 2; ++kt){
      bf16x8 af[4], bfr[4];
      #pragma unroll
      for (int i = 0; i < 4; ++i){
        af[i]  = *(const bf16x8*)&As[wm_ * 64 + i * 16 + c16][kt * 32 + quad * 8];
        bfr[i] = *(const bf16x8*)&Bs[wn_ * 64 + i * 16 + c16][kt * 32 + quad * 8];
      }
      #pragma unroll
      for (int i = 0; i < 4; ++i)
        #pragma unroll
        for (int j = 0; j < 4; ++j)
          acc[i][j] = __builtin_amdgcn_mfma_f32_16x16x32_bf16(af[i], bfr[j], acc[i][j], 0, 0, 0);
    }
  }
  #pragma unroll
  for (int i = 0; i < 4; ++i)
    #pragma unroll
    for (int j = 0; j < 4; ++j){
      int colg = n0 + wn_ * 64 + j * 16 + c16;
      #pragma unroll
      for (int r = 0; r < 4; ++r){
        int row = m0 + wm_ * 64 + i * 16 + quad * 4 + r;
        Cp[(size_t)row * 2048 + colg] = acc[i][j][r];
      }
    }
}

// ---------------------------------------------------------------------------
// k_recur R10. Record buffers (256 KB total, at OFF_H):
//   rec[dir][chain g][buf][sample s 0..15][wg 0..127] = {h01, h23, tag, 0}
//     16 B; base offset ((dir*2+g)*2+buf) << 15.
// Protocol per chain (R5's): buf[t&1] with tag==t is the h input of step t.
//   Tag-0 zero records into buf0 at start; tag t+1 into buf[(t+1)&1] fired by
//   the CELL WAVE itself right after computing h (shuffle-packed record, one
//   sc0sc1 dwordx4, no drain, no flag, no S3 wait). Readers poll their own
//   fragment records until all tags == t, with s_sleep(8) backoff from round
//   2 on (thins the reader convoy on the line the producer must write).
// Launch/overwrite safety arguments unchanged from R9/R5.
// wg is XCD-swizzled (xproj/out 64B-line locality).
// ---------------------------------------------------------------------------
__global__ __launch_bounds__(256, 1) void k_recur(
    const __bf16* __restrict__ whhp,
    const float*  __restrict__ xproj,   // [2][32][256][2048]
    const float*  __restrict__ biasm,   // [2][32][2048]
    const float*  __restrict__ cb,      // [32][8]
    const int*    __restrict__ lens,    // [32]
    char* hrec,                         // record region (see above)
    float* __restrict__ out)            // [32][256][1024]
{
  const int tid = threadIdx.x, lane = tid & 63, wv = tid >> 6;
  const int quad = lane >> 4, c16 = lane & 15;
  const int bid = blockIdx.x, dir = bid >> 7;
  const int b7 = bid & 127;
  const int wg = ((b7 & 7) << 4) | (b7 >> 3);   // XCD-aware swizzle
  const int hidx0 = wg * 4;

  // basis-weight B fragments -> registers (logical-wg indexed)
  bf16x8 bfrag[4][8];
  {
    const __bf16* base = whhp + (size_t)((dir * 128 + wg) * 4 + wv) * 4 * (8 * 512);
    #pragma unroll
    for (int kt = 0; kt < 4; ++kt)
      #pragma unroll
      for (int n = 0; n < 8; ++n)
        bfrag[kt][n] = *(const bf16x8*)(base + (size_t)(kt * 8 + n) * 512 + lane * 8);
  }
  // c_batch columns for this lane's accumulator rows, per chain
  f32x4 ccv[2][8];
  #pragma unroll
  for (int g = 0; g < 2; ++g)
    #pragma unroll
    for (int n = 0; n < 8; ++n){
      f32x4 v;
      #pragma unroll
      for (int r = 0; r < 4; ++r) v[r] = cb[(g * 16 + quad * 4 + r) * 8 + n];
      ccv[g][n] = v;
    }

  // cell-thread state (tid < 64 = wave 0): sample s_ in chain, channel jj2
  const int s_ = tid >> 2, jj2 = tid & 3;
  float bias_gc[2][4] = {{0,0,0,0},{0,0,0,0}};
  int   mylen[2] = {0, 0};
  float cst[2] = {0.f, 0.f};
  if (tid < 64){
    #pragma unroll
    for (int g = 0; g < 2; ++g){
      #pragma unroll
      for (int gg = 0; gg < 4; ++gg)
        bias_gc[g][gg] = biasm[(size_t)(dir * 32 + g * 16 + s_) * 2048
                               + gg * 512 + hidx0 + jj2];
      mylen[g] = lens[g * 16 + s_];
    }
  }

  __shared__ float red[4][64][4];
  __shared__ float xg[32][4][4];
  __shared__ float outst[16][4];

  // init: lanes 192..223 publish zero-records (tag 0) into buf0, both chains
  if (tid >= 192 && tid < 224){
    int i = tid - 192, gi = i >> 4, sg = i & 15;
    u32x4 z = {0u, 0u, 0u, 0u};
    u32x4* wb = (u32x4*)(hrec + (((size_t)(dir * 2 + gi) * 2 + 0) << 15));
    st_b128_coh(wb + sg * 128 + wg, z);
  }

  // prefetch xproj for step 0 (normal cached load; waves 0-1)
  f32x4 pf = {0, 0, 0, 0};
  const int b_pf = tid >> 2, g_pf = tid & 3;
  if (tid < 128){
    int to0 = dir ? (TT - 1) : 0;
    pf = *(const f32x4*)(xproj + ((size_t)(dir * 32 + b_pf) * TT + to0) * 2048
                         + g_pf * 512 + hidx0);
  }

  // per-lane record indices (units of 16 B records), per kt: sample = c16,
  // channels (wv*4+kt)*32 + quad*8 .. +8 = records (wg0, wg0+1)
  int ridx[4];
  #pragma unroll
  for (int kt = 0; kt < 4; ++kt)
    ridx[kt] = c16 * 128 + (wv * 4 + kt) * 8 + quad * 2;

  for (int t = 0; t < TT; ++t){
    const int to = dir ? (TT - 1 - t) : t;
    const unsigned tgt = (unsigned)t;

    #pragma unroll
    for (int g = 0; g < 2; ++g){
      const u32x4* rb = (const u32x4*)(hrec
                        + (((size_t)(dir * 2 + g) * 2 + (t & 1)) << 15));

      // ---- poll-load fragment records until all tags == t (with backoff) --
      u32x4 r0[4], r1[4];
      int rnd = 0;
      while (true){
        #pragma unroll
        for (int p = 0; p < 4; ++p){
          r0[p] = ld_b128_coh(rb + ridx[p]);
          r1[p] = ld_b128_coh(rb + ridx[p] + 1);
        }
        asm volatile("s_waitcnt vmcnt(0)"
                     : "+v"(r0[0]), "+v"(r0[1]), "+v"(r0[2]), "+v"(r0[3]),
                       "+v"(r1[0]), "+v"(r1[1]), "+v"(r1[2]), "+v"(r1[3])
                     :: "memory");
        unsigned bad = 0;
        #pragma unroll
        for (int p = 0; p < 4; ++p)
          bad |= (r0[p][2] ^ tgt) | (r1[p][2] ^ tgt);
        if (__all((int)(bad == 0u))) break;
        if (rnd >= 2) __builtin_amdgcn_s_sleep(8);   // ~512 cyc backoff
        ++rnd;
      }
      bf16x8 af[4];
      #pragma unroll
      for (int p = 0; p < 4; ++p){
        u32x4 w = {r0[p][0], r0[p][1], r1[p][0], r1[p][1]};
        af[p] = __builtin_bit_cast(bf16x8, w);
      }

      // ---- MFMA: h(16 samples) x basis weights, mix over basis ----
      f32x4 acc[8];
      #pragma unroll
      for (int n = 0; n < 8; ++n) acc[n] = (f32x4){0,0,0,0};
      #pragma unroll
      for (int kt = 0; kt < 4; ++kt)
        #pragma unroll
        for (int n = 0; n < 8; ++n)
          acc[n] = __builtin_amdgcn_mfma_f32_16x16x32_bf16(af[kt], bfrag[kt][n], acc[n], 0, 0, 0);
      f32x4 mix = {0,0,0,0};
      #pragma unroll
      for (int n = 0; n < 8; ++n) mix += ccv[g][n] * acc[n];
      *(f32x4*)&red[wv][lane][0] = mix;
      if (g == 0 && tid < 128)
        *(f32x4*)&xg[b_pf][g_pf][0] = pf;   // xproj for ALL 32 samples, step t
      __syncthreads();   // S2: red/xg ready

      // ---- cell (wave 0): 16 samples x 4 channels; publish immediately ----
      if (tid < 64){
        const int qp = s_ >> 2, rg = s_ & 3;
        float gv[4];
        #pragma unroll
        for (int gg = 0; gg < 4; ++gg){
          int li = qp * 16 + gg * 4 + jj2;
          float s = red[0][li][rg] + red[1][li][rg]
                  + red[2][li][rg] + red[3][li][rg];
          gv[gg] = s + xg[g * 16 + s_][gg][jj2] + bias_gc[g][gg];
        }
        float i_ = sigm(gv[0]);
        float f_ = sigm(gv[1]);
        float g_ = tanh_(gv[2]);
        float o_ = sigm(gv[3]);
        bool valid = (to < mylen[g]);
        float cy = valid ? (f_ * cst[g] + i_ * g_) : 0.f;
        float hy = valid ? (o_ * tanh_(cy)) : 0.f;
        cst[g] = cy;
        outst[s_][jj2] = hy;

        // shuffle-pack the 16 B record {h01,h23,tag,0} and fire it now
        unsigned hu = (unsigned)__builtin_bit_cast(unsigned short, f2bf(hy));
        unsigned hx = __shfl_xor(hu, 1, 64);
        unsigned dpair = (jj2 & 1) ? (hx | (hu << 16)) : (hu | (hx << 16));
        unsigned dothr = __shfl_xor(dpair, 2, 64);
        if (jj2 == 0){
          u32x4 rec = {dpair, dothr, (unsigned)(t + 1), 0u};
          u32x4* wb = (u32x4*)(hrec
                      + (((size_t)(dir * 2 + g) * 2 + ((t + 1) & 1)) << 15));
          st_b128_coh(wb + s_ * 128 + wg, rec);
        }
      }
      __syncthreads();   // S3: outst ready

      // ---- out store for this chain's 16 samples (wave 2) ----
      if (tid >= 128 && tid < 144){
        int sg = tid - 128;
        *(f32x4*)(out + ((size_t)(g * 16 + sg) * TT + to) * 1024
                  + dir * 512 + hidx0)
            = *(f32x4*)&outst[sg][0];
      }
      // ---- end of phase B: prefetch next step's xproj (cached) ----
      if (g == 1 && t < TT - 1 && tid < 128){
        int ton = dir ? (TT - 2 - t) : (t + 1);
        pf = *(const f32x4*)(xproj + ((size_t)(dir * 32 + b_pf) * TT + ton) * 2048
                             + g_pf * 512 + hidx0);
      }
    }
  }
}

// ---------------------------------------------------------------------------
extern "C" void kernel_launch(void* const* d_in, const int* in_sizes, int n_in,
                              void* d_out, int out_size, void* d_ws, size_t ws_size,
                              hipStream_t stream)
{
  const float* x      = (const float*)d_in[0];
  const void*  mask   = d_in[1];
  const int*   meta_a = (const int*)d_in[2];
  const int*   meta_c = (const int*)d_in[3];
  const float* emb_a  = (const float*)d_in[4];
  const float* emb_c  = (const float*)d_in[5];
  const float* P_W1   = (const float*)d_in[6];
  const float* P_b1   = (const float*)d_in[7];
  const float* P_W2   = (const float*)d_in[8];
  const float* W_ih   = (const float*)d_in[9];
  const float* W_hh   = (const float*)d_in[10];
  const float* bias_f = (const float*)d_in[11];
  const float* W_ih_r = (const float*)d_in[12];
  const float* W_hh_r = (const float*)d_in[13];
  const float* bias_r = (const float*)d_in[14];
  float* out = (float*)d_out;
  char* ws = (char*)d_ws;

  constexpr size_t OFF_C     = 0;           //   1 KB  c_batch
  constexpr size_t OFF_LEN   = 1024;        //  128 B  lengths
  constexpr size_t OFF_BIAS  = 4096;        //  512 KB mixed biases
  constexpr size_t OFF_H     = 528384;      //  256 KB tagged h records
  constexpr size_t OFF_WHHP  = 790528;      // 33.5 MB basis Whh fragments
  constexpr size_t OFF_XBF   = 34344960;    //  8.4 MB x bf16
  constexpr size_t OFF_WIHM  = 42733568;    //   67 MB mixed Wih (per-dir reuse)
  constexpr size_t OFF_XPROJ = 109842432;   //  134 MB xproj f32 (both dirs)
  constexpr size_t WS_NEED   = 244060160;
  if (ws_size < WS_NEED) return;

  float*   c_b   = (float*)(ws + OFF_C);
  int*     lens  = (int*)(ws + OFF_LEN);
  float*   biasm = (float*)(ws + OFF_BIAS);
  char*    hrec  = (char*)(ws + OFF_H);
  __bf16*  whhp  = (__bf16*)(ws + OFF_WHHP);
  __bf16*  xbf   = (__bf16*)(ws + OFF_XBF);
  __bf16*  wihm  = (__bf16*)(ws + OFF_WIHM);
  float*   xproj = (float*)(ws + OFF_XPROJ);

  k_meta<<<1, 256, 0, stream>>>(mask, meta_a, meta_c, emb_a, emb_c,
                                P_W1, P_b1, P_W2, c_b, lens);
  k_xbf<<<2048, 256, 0, stream>>>(x, xbf);
  k_whhp<<<8192, 256, 0, stream>>>(W_hh, W_hh_r, whhp);
  k_bias<<<512, 256, 0, stream>>>(bias_f, bias_r, c_b, biasm);
  for (int dir = 0; dir < 2; ++dir){
    k_mixwih<<<512, 256, 0, stream>>>(dir ? W_ih_r : W_ih, c_b, wihm);
    k_gemm<<<1024, 256, 0, stream>>>(xbf, wihm,
                                     xproj + (size_t)dir * 32 * TT * 2048);
  }
  k_recur<<<256, 256, 0, stream>>>(whhp, xproj, biasm, c_b, lens, hrec, out);
}